// Round 1
// baseline (883.349 us; speedup 1.0000x reference)
//
#include <hip/hip_runtime.h>
#include <math.h>

// Decoder: B=32, S=2048, H=1024, V=32000, L=2 (fp32 in/out)
//
// Key algebraic optimization: scores = enc . (h1 @ W_attn) + const(b);
// the per-row constant (b_attn . h1) cancels in softmax -> b_attn unused,
// and the 137-GFLOP proj matmul is replaced by a 67-MFLOP one. enc (268 MB)
// is read exactly once in a fused flash-style scores+softmax+context pass.

#define Bq 32
#define Sq 2048
#define Hq 1024
#define Vq 32000

// d_out float offsets: [output BxV][context BxH][new_hidden 2xBxH][attn BxS]
#define CTX_OFF   1024000
#define NEWH_OFF  1056768
#define ATTN_OFF  1122304

// ---- workspace float offsets ----
// Phase-1 region (GRU partial slabs), later reused by the logits phase:
#define WS_GI0P   0            // 16*32*3072 = 1572864
#define WS_GH0P   1572864      //  8*32*3072 =  786432
#define WS_GI1P   2359296      //  8*32*3072
#define WS_GH1P   3145728      //  8*32*3072   (region A ends at 3932160)
//   reuse of region A after GRUs are done:
#define WS_LP     0            // 2*32*32000 = 2048000
#define WS_LOGITS 2048000      // 32*32000   = 1024000
#define WS_PMAX   3072000      // 256
#define WS_PSUM   3072256      // 256
// persistent small buffers:
#define WS_H0     3932160      // 32768
#define WS_CAT    3964928      // 32*2048 (h1 | context)
#define WS_RNNIN  4030464      // 32*2048
#define WS_VP     4096000      // 8*32*1024 = 262144
#define WS_SCORES 4358144      // 32*2048
#define WS_PM     4423680      // 1024
#define WS_PL     4424704      // 1024
#define WS_PCTX   4425728      // 32*32*1024 = 1048576
// total: 5474304 floats = 21.9 MB

// ---------------- rnn_in = [emb[ids] | last_context] : [32][2048] -------------
__global__ __launch_bounds__(256) void build_rnn_in_k(const int* __restrict__ ids,
                                                      const float* __restrict__ emb,
                                                      const float* __restrict__ lc,
                                                      float* __restrict__ rnn_in) {
    int idx = blockIdx.x * 256 + threadIdx.x;      // [0, 65536)
    int b = idx >> 11, k = idx & 2047;
    float v;
    if (k < Hq) v = emb[(size_t)ids[b] * Hq + k];
    else        v = lc[b * Hq + (k - Hq)];
    rnn_in[idx] = v;
}

// ---------------- generic split-K skinny matmul partial ----------------------
// P[ks][b][r] = sum_{k in [ks*Kc,(ks+1)*Kc)} A[b][k] * W[r][k]
// block tile: 128 rows x 32 batch; thread micro-tile 4b x 4r.
// LDS is k-major so compute reads are float4 (ds_read_b128), A reads broadcast.
__global__ __launch_bounds__(256) void mm_partial_k(const float* __restrict__ A,
                                                    const float* __restrict__ W,
                                                    float* __restrict__ P,
                                                    int R, int K, int Kc, int nrb) {
    __shared__ __align__(16) float Al[32 * 36];    // [k][b], stride 36
    __shared__ __align__(16) float Wl[32 * 132];   // [k][r], stride 132
    int bx = blockIdx.x;
    int rb = bx % nrb, ks = bx / nrb;
    int r0 = rb * 128, k0 = ks * Kc;
    int tid = threadIdx.x;
    int bi = tid >> 5, rj = tid & 31;              // b-group 0..7, r-group 0..31
    float acc[4][4] = {{0.f}};
    for (int kc = k0; kc < k0 + Kc; kc += 32) {
        for (int idx = tid; idx < 1024; idx += 256) {       // A: 32b x 32k
            int b = idx >> 5, k = idx & 31;
            Al[k * 36 + b] = A[b * K + kc + k];
        }
        for (int idx = tid; idx < 4096; idx += 256) {       // W: 128r x 32k
            int r = idx >> 5, k = idx & 31;
            Wl[k * 132 + r] = W[(size_t)(r0 + r) * K + kc + k];
        }
        __syncthreads();
        #pragma unroll
        for (int k = 0; k < 32; k++) {
            float4 a4 = *(const float4*)&Al[k * 36 + bi * 4];
            float4 w4 = *(const float4*)&Wl[k * 132 + rj * 4];
            acc[0][0] += a4.x * w4.x; acc[0][1] += a4.x * w4.y; acc[0][2] += a4.x * w4.z; acc[0][3] += a4.x * w4.w;
            acc[1][0] += a4.y * w4.x; acc[1][1] += a4.y * w4.y; acc[1][2] += a4.y * w4.z; acc[1][3] += a4.y * w4.w;
            acc[2][0] += a4.z * w4.x; acc[2][1] += a4.z * w4.y; acc[2][2] += a4.z * w4.z; acc[2][3] += a4.z * w4.w;
            acc[3][0] += a4.w * w4.x; acc[3][1] += a4.w * w4.y; acc[3][2] += a4.w * w4.z; acc[3][3] += a4.w * w4.w;
        }
        __syncthreads();
    }
    size_t base = (size_t)ks * 32 * R;
    #pragma unroll
    for (int bb = 0; bb < 4; bb++) {
        int b = bi * 4 + bb;
        float4 o = make_float4(acc[bb][0], acc[bb][1], acc[bb][2], acc[bb][3]);
        *(float4*)&P[base + (size_t)b * R + r0 + rj * 4] = o;
    }
}

// ---------------- GRU gate nonlinearity --------------------------------------
__global__ __launch_bounds__(256) void gru_gate_k(const float* __restrict__ gip,
                                                  const float* __restrict__ ghp,
                                                  int nsi, int nsh,
                                                  const float* __restrict__ bih,
                                                  const float* __restrict__ bhh,
                                                  const float* __restrict__ hprev,
                                                  float* __restrict__ out_newh,
                                                  float* __restrict__ out_ws, int ws_stride) {
    int idx = blockIdx.x * 256 + threadIdx.x;      // [0, 32768)
    int b = idx >> 10, j = idx & 1023;
    float ir = bih[j], iz = bih[1024 + j], in_ = bih[2048 + j];
    for (int s = 0; s < nsi; s++) {
        const float* p = gip + (size_t)s * 32 * 3072 + b * 3072;
        ir += p[j]; iz += p[1024 + j]; in_ += p[2048 + j];
    }
    float hr = bhh[j], hz = bhh[1024 + j], hn = bhh[2048 + j];
    for (int s = 0; s < nsh; s++) {
        const float* p = ghp + (size_t)s * 32 * 3072 + b * 3072;
        hr += p[j]; hz += p[1024 + j]; hn += p[2048 + j];
    }
    float r = 1.f / (1.f + __expf(-(ir + hr)));
    float z = 1.f / (1.f + __expf(-(iz + hz)));
    float n = tanhf(in_ + r * hn);
    float hp = hprev[idx];
    float h = (1.f - z) * n + z * hp;
    out_newh[idx] = h;
    out_ws[b * ws_stride + j] = h;
}

// ---------------- v = h1 @ W_attn (split over i) -----------------------------
// vp[is][b][k] = sum_{i in chunk} h1[b][i] * W_attn[i][k]
__global__ __launch_bounds__(256) void wv_partial_k(const float* __restrict__ h1, int h1_stride,
                                                    const float* __restrict__ Wa,
                                                    float* __restrict__ vp) {
    __shared__ float h1l[32 * 128];                // [b][i]
    int bx = blockIdx.x;
    int kt = bx & 15, is = bx >> 4;                // 16 k-tiles x 8 i-splits
    int k0 = kt * 64, i0 = is * 128;
    int tid = threadIdx.x;
    for (int idx = tid; idx < 4096; idx += 256) {  // 32b x 128i, coalesced on i
        int b = idx >> 7, i = idx & 127;
        h1l[b * 128 + i] = h1[b * h1_stride + i0 + i];
    }
    __syncthreads();
    int kk = tid & 63, bg = tid >> 6;              // wave = 64 consecutive k
    float acc[8] = {0.f};
    #pragma unroll 4
    for (int i = 0; i < 128; i++) {
        float w = Wa[(size_t)(i0 + i) * Hq + k0 + kk];
        #pragma unroll
        for (int t = 0; t < 8; t++)
            acc[t] += w * h1l[(bg * 8 + t) * 128 + i];   // wave-uniform broadcast
    }
    #pragma unroll
    for (int t = 0; t < 8; t++)
        vp[(size_t)is * (32 * Hq) + (bg * 8 + t) * Hq + k0 + kk] = acc[t];
}

// ---------------- fused scores + online softmax + context over enc -----------
// grid: 32 b x 32 s-blocks of 64 rows; wave-per-row; ctx kept 16 floats/lane.
__global__ __launch_bounds__(256) void flash_attn_k(const float* __restrict__ enc,
                                                    const float* __restrict__ vp,
                                                    float* __restrict__ scores,
                                                    float* __restrict__ pm,
                                                    float* __restrict__ pl,
                                                    float* __restrict__ pctx) {
    __shared__ __align__(16) float lctx[4 * 1024];
    __shared__ float lm[4], ll[4];
    int bx = blockIdx.x;
    int b = bx >> 5, sb = bx & 31;
    int tid = threadIdx.x;
    int w = tid >> 6, lane = tid & 63;
    // v[b][h] for this lane's 16 h's (h = i*256 + lane*4 + {0..3}); sum 8 splits
    float4 v4[4];
    #pragma unroll
    for (int i = 0; i < 4; i++) {
        float4 a = make_float4(0.f, 0.f, 0.f, 0.f);
        for (int is = 0; is < 8; is++) {
            float4 t = *(const float4*)&vp[(size_t)is * (32 * Hq) + b * Hq + i * 256 + lane * 4];
            a.x += t.x; a.y += t.y; a.z += t.z; a.w += t.w;
        }
        v4[i] = a;
    }
    float m = -INFINITY, l = 0.f;
    float4 ctx[4];
    #pragma unroll
    for (int i = 0; i < 4; i++) ctx[i] = make_float4(0.f, 0.f, 0.f, 0.f);

    #pragma unroll 2
    for (int j = 0; j < 16; j++) {
        int s = sb * 64 + w + 4 * j;
        const float4* ep = (const float4*)(enc + ((size_t)b * Sq + s) * Hq);
        float4 e[4];
        #pragma unroll
        for (int i = 0; i < 4; i++) e[i] = ep[i * 64 + lane];
        float d = 0.f;
        #pragma unroll
        for (int i = 0; i < 4; i++)
            d += e[i].x * v4[i].x + e[i].y * v4[i].y + e[i].z * v4[i].z + e[i].w * v4[i].w;
        #pragma unroll
        for (int off = 1; off < 64; off <<= 1)
            d += __shfl_xor(d, off, 64);           // butterfly: all lanes get dot
        if (lane == 0) scores[b * Sq + s] = d;
        float mn = fmaxf(m, d);
        float f = __expf(m - mn);                  // exp(-inf)=0 on first iter
        float p = __expf(d - mn);
        l = l * f + p;
        #pragma unroll
        for (int i = 0; i < 4; i++) {
            ctx[i].x = ctx[i].x * f + p * e[i].x;
            ctx[i].y = ctx[i].y * f + p * e[i].y;
            ctx[i].z = ctx[i].z * f + p * e[i].z;
            ctx[i].w = ctx[i].w * f + p * e[i].w;
        }
        m = mn;
    }
    // combine 4 waves
    #pragma unroll
    for (int i = 0; i < 4; i++)
        *(float4*)&lctx[w * 1024 + i * 256 + lane * 4] = ctx[i];
    if (lane == 0) { lm[w] = m; ll[w] = l; }
    __syncthreads();
    float M = fmaxf(fmaxf(lm[0], lm[1]), fmaxf(lm[2], lm[3]));
    float f0 = __expf(lm[0] - M), f1 = __expf(lm[1] - M);
    float f2 = __expf(lm[2] - M), f3 = __expf(lm[3] - M);
    float4 c0 = *(const float4*)&lctx[0 * 1024 + tid * 4];
    float4 c1 = *(const float4*)&lctx[1 * 1024 + tid * 4];
    float4 c2 = *(const float4*)&lctx[2 * 1024 + tid * 4];
    float4 c3 = *(const float4*)&lctx[3 * 1024 + tid * 4];
    float4 oc;
    oc.x = f0 * c0.x + f1 * c1.x + f2 * c2.x + f3 * c3.x;
    oc.y = f0 * c0.y + f1 * c1.y + f2 * c2.y + f3 * c3.y;
    oc.z = f0 * c0.z + f1 * c1.z + f2 * c2.z + f3 * c3.z;
    oc.w = f0 * c0.w + f1 * c1.w + f2 * c2.w + f3 * c3.w;
    *(float4*)&pctx[(size_t)(b * 32 + sb) * 1024 + tid * 4] = oc;
    if (tid == 0) {
        pm[b * 32 + sb] = M;
        pl[b * 32 + sb] = f0 * ll[0] + f1 * ll[1] + f2 * ll[2] + f3 * ll[3];
    }
}

// ---------------- attention finalize: context + attn weights -----------------
__global__ __launch_bounds__(256) void attn_final_k(const float* __restrict__ pm,
                                                    const float* __restrict__ pl,
                                                    const float* __restrict__ pctx,
                                                    const float* __restrict__ scores,
                                                    float* __restrict__ d_out,
                                                    float* __restrict__ cat) {
    int b = blockIdx.x, tid = threadIdx.x;
    float M = -INFINITY;
    #pragma unroll
    for (int i = 0; i < 32; i++) M = fmaxf(M, pm[b * 32 + i]);
    float fs[32];
    float L = 0.f;
    #pragma unroll
    for (int i = 0; i < 32; i++) { fs[i] = __expf(pm[b * 32 + i] - M); L += fs[i] * pl[b * 32 + i]; }
    float invL = 1.f / L;
    for (int h = tid; h < Hq; h += 256) {
        float c = 0.f;
        #pragma unroll
        for (int i = 0; i < 32; i++) c += fs[i] * pctx[(size_t)(b * 32 + i) * 1024 + h];
        c *= invL;
        d_out[CTX_OFF + b * Hq + h] = c;
        cat[b * 2048 + Hq + h] = c;
    }
    for (int s = tid; s < Sq; s += 256)
        d_out[ATTN_OFF + b * Sq + s] = __expf(scores[b * Sq + s] - M) * invL;
}

// ---------------- logits reduce + per-chunk softmax partials -----------------
__global__ __launch_bounds__(256) void logits_pass1_k(const float* __restrict__ lp,
                                                      const float* __restrict__ b_out,
                                                      float* __restrict__ logits,
                                                      float* __restrict__ pmax,
                                                      float* __restrict__ psum) {
    __shared__ float sm[256], sl[256];
    int bx = blockIdx.x;
    int b = bx >> 3, vc = bx & 7;
    int v0 = vc * 4000;
    int tid = threadIdx.x;
    float lg[16];
    float lmax = -INFINITY;
    #pragma unroll
    for (int t = 0; t < 16; t++) {
        int off = t * 256 + tid;
        if (off < 4000) {
            int v = v0 + off;
            float x = lp[(size_t)b * Vq + v] + lp[(size_t)32 * Vq + (size_t)b * Vq + v] + b_out[v];
            logits[(size_t)b * Vq + v] = x;
            lg[t] = x;
            lmax = fmaxf(lmax, x);
        } else lg[t] = -INFINITY;
    }
    float ls = 0.f;
    #pragma unroll
    for (int t = 0; t < 16; t++) ls += __expf(lg[t] - lmax);
    sm[tid] = lmax; sl[tid] = ls;
    __syncthreads();
    for (int off = 128; off > 0; off >>= 1) {
        if (tid < off) {
            float m1 = sm[tid], m2 = sm[tid + off];
            float Mx = fmaxf(m1, m2);
            sl[tid] = sl[tid] * __expf(m1 - Mx) + sl[tid + off] * __expf(m2 - Mx);
            sm[tid] = Mx;
        }
        __syncthreads();
    }
    if (tid == 0) { pmax[bx] = sm[0]; psum[bx] = sl[0]; }
}

__global__ __launch_bounds__(256) void softmax_final_k(const float* __restrict__ logits,
                                                       const float* __restrict__ pmax,
                                                       const float* __restrict__ psum,
                                                       float* __restrict__ d_out) {
    int bx = blockIdx.x;
    int b = bx >> 3, vc = bx & 7;
    int tid = threadIdx.x;
    float M = -INFINITY;
    #pragma unroll
    for (int i = 0; i < 8; i++) M = fmaxf(M, pmax[b * 8 + i]);
    float L = 0.f;
    #pragma unroll
    for (int i = 0; i < 8; i++) L += __expf(pmax[b * 8 + i] - M) * psum[b * 8 + i];
    float invL = 1.f / L;
    int v0 = vc * 4000;
    for (int off = tid; off < 4000; off += 256) {
        int v = v0 + off;
        d_out[(size_t)b * Vq + v] = __expf(logits[(size_t)b * Vq + v] - M) * invL;
    }
}

// -----------------------------------------------------------------------------
extern "C" void kernel_launch(void* const* d_in, const int* in_sizes, int n_in,
                              void* d_out, int out_size, void* d_ws, size_t ws_size,
                              hipStream_t stream) {
    const int*   ids  = (const int*)  d_in[0];
    const float* lc   = (const float*)d_in[1];
    const float* hid  = (const float*)d_in[2];
    const float* enc  = (const float*)d_in[3];
    const float* emb  = (const float*)d_in[4];
    const float* Wa   = (const float*)d_in[5];
    // d_in[6] = b_attn: adds a per-(b) constant to scores -> cancels in softmax. Unused.
    const float* Wih0 = (const float*)d_in[7];
    const float* Whh0 = (const float*)d_in[8];
    const float* bih0 = (const float*)d_in[9];
    const float* bhh0 = (const float*)d_in[10];
    const float* Wih1 = (const float*)d_in[11];
    const float* Whh1 = (const float*)d_in[12];
    const float* bih1 = (const float*)d_in[13];
    const float* bhh1 = (const float*)d_in[14];
    const float* Wout = (const float*)d_in[15];
    const float* bout = (const float*)d_in[16];
    float* out = (float*)d_out;
    float* ws  = (float*)d_ws;

    float* gi0p   = ws + WS_GI0P;
    float* gh0p   = ws + WS_GH0P;
    float* gi1p   = ws + WS_GI1P;
    float* gh1p   = ws + WS_GH1P;
    float* h0buf  = ws + WS_H0;
    float* cat    = ws + WS_CAT;
    float* rnnin  = ws + WS_RNNIN;
    float* vp     = ws + WS_VP;
    float* scores = ws + WS_SCORES;
    float* pm     = ws + WS_PM;
    float* pl     = ws + WS_PL;
    float* pctx   = ws + WS_PCTX;
    float* lpbuf  = ws + WS_LP;      // aliases GRU slabs (dead by then)
    float* logits = ws + WS_LOGITS;
    float* pmax   = ws + WS_PMAX;
    float* psum   = ws + WS_PSUM;

    // 1) rnn_in = [emb gather | last_context]
    build_rnn_in_k<<<256, 256, 0, stream>>>(ids, emb, lc, rnnin);
    // 2) GRU layer 0 matmul partials (gi: K=2048 ksplit=16; gh: K=1024 ksplit=8)
    mm_partial_k<<<384, 256, 0, stream>>>(rnnin, Wih0, gi0p, 3072, 2048, 128, 24);
    mm_partial_k<<<192, 256, 0, stream>>>(hid,   Whh0, gh0p, 3072, 1024, 128, 24);
    // 3) gate 0 -> h0 (d_out new_hidden[0] + ws)
    gru_gate_k<<<128, 256, 0, stream>>>(gi0p, gh0p, 16, 8, bih0, bhh0, hid,
                                        out + NEWH_OFF, h0buf, 1024);
    // 4) GRU layer 1
    mm_partial_k<<<192, 256, 0, stream>>>(h0buf,        Wih1, gi1p, 3072, 1024, 128, 24);
    mm_partial_k<<<192, 256, 0, stream>>>(hid + 32768,  Whh1, gh1p, 3072, 1024, 128, 24);
    gru_gate_k<<<128, 256, 0, stream>>>(gi1p, gh1p, 8, 8, bih1, bhh1, hid + 32768,
                                        out + NEWH_OFF + 32768, cat, 2048);  // h1 -> cat[:, :1024]
    // 5) v = h1 @ W_attn (partials over i)
    wv_partial_k<<<128, 256, 0, stream>>>(cat, 2048, Wa, vp);
    // 6) fused scores + online softmax + context over enc (single enc read)
    flash_attn_k<<<1024, 256, 0, stream>>>(enc, vp, scores, pm, pl, pctx);
    // 7) finalize: context -> d_out + cat[:, 1024:], attn weights -> d_out
    attn_final_k<<<32, 256, 0, stream>>>(pm, pl, pctx, scores, out, cat);
    // 8) logits = cat @ W_out.T (split-K=2), then softmax over V
    mm_partial_k<<<500, 256, 0, stream>>>(cat, Wout, lpbuf, 32000, 2048, 1024, 250);
    logits_pass1_k<<<256, 256, 0, stream>>>(lpbuf, bout, logits, pmax, psum);
    softmax_final_k<<<256, 256, 0, stream>>>(logits, pmax, psum, out);
}